// Round 1
// baseline (846.303 us; speedup 1.0000x reference)
//
#include <hip/hip_runtime.h>
#include <cstdint>

#pragma clang fp contract(off)

#define TPB 256
typedef unsigned int uint32;
typedef unsigned long long u64;

constexpr int BB = 256;    // batch
constexpr int NN = 8732;   // boxes
constexpr int CC = 21;     // classes
constexpr int KK = 200;    // top-k
constexpr int CH = (NN + TPB - 1) / TPB;  // 35 elems per thread chunk

// ---------------- shared memory layout ----------------
struct NmsS {
  float bx1[256], by1[256], bx2[256], by2[256], barea[256], bscore[256]; // 6144 B
  u64 mask[KK][4];                                                      // 6400 B
};
struct SmemT {
  union UU {
    uint32 keys[NN];   // 34928 B  (radix-select phase)
    NmsS nms;          // 12544 B  (NMS phase, keys dead by then)
  } u;
  uint32 hist[2048];
  uint32 sc[256];
  uint32 bc[2];
  uint32 cnt;
  u64 cand[256];
};
static_assert(sizeof(SmemT) <= 48 * 1024, "LDS budget");

// monotone sortable key; masked(-1.0f) maps to 0x407FFFFF (= ~bits(-1.0f)),
// all probs > 0.01 map to bits|0x80000000 (strictly larger).
__device__ __forceinline__ uint32 key_of(float p) {
  return (p > 0.01f) ? (__float_as_uint(p) | 0x80000000u) : 0x407FFFFFu;
}

// find largest bin b with suffix-count(>=b) >= target; returns bin and count(>b)
__device__ void suffix_find(SmemT& sm, int nbins, uint32 target,
                            uint32& pivot, uint32& cntgt) {
  const int t = threadIdx.x;
  const int chunk = nbins >> 8;     // 8 or 4
  const int base = t * chunk;
  uint32 part = 0;
  for (int i = 0; i < chunk; ++i) part += sm.hist[base + i];
  sm.sc[t] = part;
  __syncthreads();
  for (int off = 1; off < 256; off <<= 1) {   // inclusive suffix scan
    uint32 v = (t + off < 256) ? sm.sc[t + off] : 0u;
    __syncthreads();
    sm.sc[t] += v;
    __syncthreads();
  }
  uint32 mine = sm.sc[t];
  uint32 nxt = (t < 255) ? sm.sc[t + 1] : 0u;
  if (mine >= target && nxt < target) {       // unique crossing chunk
    uint32 acc = nxt;
    for (int bin = base + chunk - 1; bin >= base; --bin) {
      uint32 h = sm.hist[bin];
      if (acc + h >= target) { sm.bc[0] = (uint32)bin; sm.bc[1] = acc; break; }
      acc += h;
    }
  }
  __syncthreads();
  pivot = sm.bc[0];
  cntgt = sm.bc[1];
  __syncthreads();
}

// ---------------- kernel 1: canonical double-precision softmax ----------------
// MODE 0: write transposed probs [b][c-1][n] (classes 1..20)
// MODE 1: write per-(b,n) double2 {max, 1/S}
template <int MODE>
__global__ __launch_bounds__(TPB) void prep_kernel(const float* __restrict__ conf,
                                                   float* __restrict__ probsT,
                                                   double2* __restrict__ ms) {
  const int n = blockIdx.x * TPB + threadIdx.x;
  const int b = blockIdx.y;
  if (n >= NN) return;
  const float* cp = conf + ((size_t)b * NN + n) * CC;
  float xs[CC];
#pragma unroll
  for (int j = 0; j < CC; ++j) xs[j] = cp[j];
  float mx = xs[0];
#pragma unroll
  for (int j = 1; j < CC; ++j) mx = fmaxf(mx, xs[j]);
  double es[CC];
  double S = 0.0;
#pragma unroll
  for (int j = 0; j < CC; ++j) {
    es[j] = exp((double)xs[j] - (double)mx);
    S += es[j];
  }
  double Sinv = 1.0 / S;
  if (MODE == 0) {
#pragma unroll
    for (int c2 = 1; c2 < CC; ++c2)
      probsT[((size_t)b * 20 + (c2 - 1)) * NN + n] = (float)(es[c2] * Sinv);
  } else {
    ms[(size_t)b * NN + n] = make_double2((double)mx, Sinv);
  }
}

// ---------------- kernel 2: per-(b,c) top-k + NMS + output ----------------
template <int MODE>
__global__ __launch_bounds__(TPB) void nms_kernel(
    const float* __restrict__ probsT, const float* __restrict__ conf,
    const double2* __restrict__ ms, const float* __restrict__ loc,
    const float* __restrict__ dbox, float* __restrict__ out) {
  __shared__ SmemT sm;
  const int t = threadIdx.x;
  // XCD-locality swizzle: 21 tasks of one b land on one XCD residue in sequence
  const int tb = blockIdx.x;
  const int xcd = tb & 7;
  const int s0 = tb >> 3;
  const int bi = s0 / CC;
  const int c = s0 - bi * CC;
  const int b = bi * 8 + xcd;
  const size_t outbase = (size_t)(b * CC + c) * KK * 5;

  if (c == 0) {  // reference zeroes class 0
    for (int i = t; i < KK * 5; i += TPB) out[outbase + i] = 0.0f;
    return;
  }

  // ---- phase 1: build sortable keys in LDS ----
  if (MODE == 0) {
    const float* pp = probsT + ((size_t)b * 20 + (c - 1)) * NN;
    for (int n = t; n < NN; n += TPB) sm.u.keys[n] = key_of(pp[n]);
  } else if (MODE == 1) {
    for (int n = t; n < NN; n += TPB) {
      double2 mv = ms[(size_t)b * NN + n];
      float x = conf[((size_t)b * NN + n) * CC + c];
      float p = (float)(exp((double)x - mv.x) * mv.y);
      sm.u.keys[n] = key_of(p);
    }
  } else {  // fully inline fallback (tiny ws)
    for (int n = t; n < NN; n += TPB) {
      const float* cp = conf + ((size_t)b * NN + n) * CC;
      float mx = cp[0];
      for (int j = 1; j < CC; ++j) mx = fmaxf(mx, cp[j]);
      double S = 0.0, ec = 0.0;
      for (int j = 0; j < CC; ++j) {
        double e = exp((double)cp[j] - (double)mx);
        S += e;
        if (j == c) ec = e;
      }
      float p = (float)(ec * (1.0 / S));
      sm.u.keys[n] = key_of(p);
    }
  }
  __syncthreads();

  // ---- phase 2: exact 3-pass radix select for the 200th value ----
  uint32 p1, cg1, p2, cg2, p3, cg3;
  for (int i = t; i < 2048; i += TPB) sm.hist[i] = 0;
  __syncthreads();
  for (int n = t; n < NN; n += TPB) atomicAdd(&sm.hist[sm.u.keys[n] >> 21], 1u);
  __syncthreads();
  suffix_find(sm, 2048, (uint32)KK, p1, cg1);

  for (int i = t; i < 2048; i += TPB) sm.hist[i] = 0;
  __syncthreads();
  for (int n = t; n < NN; n += TPB) {
    uint32 k = sm.u.keys[n];
    if ((k >> 21) == p1) atomicAdd(&sm.hist[(k >> 10) & 2047u], 1u);
  }
  __syncthreads();
  suffix_find(sm, 2048, (uint32)KK - cg1, p2, cg2);

  const uint32 p12 = (p1 << 11) | p2;
  for (int i = t; i < 2048; i += TPB) sm.hist[i] = 0;
  __syncthreads();
  for (int n = t; n < NN; n += TPB) {
    uint32 k = sm.u.keys[n];
    if ((k >> 10) == p12) atomicAdd(&sm.hist[k & 1023u], 1u);
  }
  __syncthreads();
  suffix_find(sm, 1024, (uint32)KK - cg1 - cg2, p3, cg3);

  const uint32 T = (p12 << 10) | p3;          // exact 200th-largest key
  const uint32 cnt_gt = cg1 + cg2 + cg3;      // count strictly greater (<200)
  const uint32 m_need = (uint32)KK - cnt_gt;  // equals to take, lowest index first

  // ---- phase 3: stable selection of exactly 200 candidates ----
  sm.cand[t] = 0ull;  // padding sorts last
  if (t == 0) sm.cnt = 0u;
  __syncthreads();
  const int base = t * CH;
  const int endn = (base + CH < NN) ? (base + CH) : NN;
  for (int n = base; n < endn; ++n) {
    uint32 k = sm.u.keys[n];
    if (k > T) {
      uint32 slot = atomicAdd(&sm.cnt, 1u);
      sm.cand[slot] = ((u64)k << 32) | (uint32)(~(uint32)n);
    }
  }
  uint32 cnteq = 0;
  for (int n = base; n < endn; ++n)
    if (sm.u.keys[n] == T) ++cnteq;
  sm.sc[t] = cnteq;
  __syncthreads();
  for (int off = 1; off < 256; off <<= 1) {   // inclusive forward scan
    uint32 v = (t >= off) ? sm.sc[t - off] : 0u;
    __syncthreads();
    sm.sc[t] += v;
    __syncthreads();
  }
  uint32 g = sm.sc[t] - cnteq;  // exclusive rank among equals (index-ordered)
  for (int n = base; n < endn; ++n) {
    if (sm.u.keys[n] == T) {
      if (g < m_need) sm.cand[cnt_gt + g] = ((u64)T << 32) | (uint32)(~(uint32)n);
      ++g;
    }
  }
  __syncthreads();

  // ---- phase 4: bitonic sort 256 (key desc, idx asc via ~idx in low bits) ----
  for (int kk = 2; kk <= 256; kk <<= 1) {
    for (int j = kk >> 1; j > 0; j >>= 1) {
      int ixj = t ^ j;
      if (ixj > t) {
        u64 a = sm.cand[t];
        u64 bb = sm.cand[ixj];
        bool desc = (t & kk) == 0;
        if (desc ? (a < bb) : (a > bb)) { sm.cand[t] = bb; sm.cand[ixj] = a; }
      }
      __syncthreads();
    }
  }

  // ---- phase 5: gather + decode (exact reference fp32 op order, CR exp) ----
  if (t < KK) {
    u64 cd = sm.cand[t];
    uint32 k32 = (uint32)(cd >> 32);
    uint32 idx = ~((uint32)cd);
    bool valid = (k32 & 0x80000000u) != 0u;
    float score = valid ? __uint_as_float(k32 & 0x7fffffffu) : -1.0f;
    const float4 lc = ((const float4*)loc)[(size_t)b * NN + idx];
    const float4 db = ((const float4*)dbox)[idx];
    float cx = db.x + (lc.x * 0.1f) * db.z;
    float cy = db.y + (lc.y * 0.1f) * db.w;
    float w_ = db.z * (float)exp((double)(lc.z * 0.2f));
    float h_ = db.w * (float)exp((double)(lc.w * 0.2f));
    float x1 = cx - w_ * 0.5f;  // == wh/2.0 exactly
    float y1 = cy - h_ * 0.5f;
    float x2 = x1 + w_;
    float y2 = y1 + h_;
    sm.u.nms.bx1[t] = x1;
    sm.u.nms.by1[t] = y1;
    sm.u.nms.bx2[t] = x2;
    sm.u.nms.by2[t] = y2;
    sm.u.nms.barea[t] = (x2 - x1) * (y2 - y1);
    sm.u.nms.bscore[t] = score;
  }
  __syncthreads();

  // ---- phase 6: parallel directional IoU mask (row i: bits j with iou>0.45) ----
  if (t < KK) {
    const float xi1 = sm.u.nms.bx1[t], yi1 = sm.u.nms.by1[t];
    const float xi2 = sm.u.nms.bx2[t], yi2 = sm.u.nms.by2[t];
    const float ai = sm.u.nms.barea[t];
    for (int wq = 0; wq < 4; ++wq) {
      u64 w = 0;
      const int jend = (wq * 64 + 64 < KK) ? (wq * 64 + 64) : KK;
      for (int j = wq * 64; j < jend; ++j) {
        float xx1 = fmaxf(sm.u.nms.bx1[j], xi1);
        float yy1 = fmaxf(sm.u.nms.by1[j], yi1);
        float xx2 = fmaxf(sm.u.nms.bx2[j], xi2);
        float yy2 = fmaxf(sm.u.nms.by2[j], yi2);
        float inter = (xx2 - xx1) * (yy2 - yy1);          // NOT clamped (ref!)
        float uni = (sm.u.nms.barea[j] - inter) + ai;     // exact ref op order
        float iou = inter / uni;
        if ((iou > 0.45f) && (j != t)) w |= 1ull << (j & 63);
      }
      sm.u.nms.mask[t][wq] = w;
    }
  }
  __syncthreads();

  // ---- phase 7: greedy walk, replicated in registers on every thread ----
  u64 s0_ = 0, s1_ = 0, s2_ = 0, s3_ = 0, k0_ = 0, k1_ = 0, k2_ = 0, k3_ = 0;
  {
    for (int r = 0; r < 64; ++r)
      if (!(sm.u.nms.bscore[r] > 0.01f)) s0_ |= 1ull << r;
    for (int r = 64; r < 128; ++r)
      if (!(sm.u.nms.bscore[r] > 0.01f)) s1_ |= 1ull << (r - 64);
    for (int r = 128; r < 192; ++r)
      if (!(sm.u.nms.bscore[r] > 0.01f)) s2_ |= 1ull << (r - 128);
    for (int r = 192; r < KK; ++r)
      if (!(sm.u.nms.bscore[r] > 0.01f)) s3_ |= 1ull << (r - 192);
    u64 n0 = sm.u.nms.mask[0][0], n1 = sm.u.nms.mask[0][1];
    u64 n2 = sm.u.nms.mask[0][2], n3 = sm.u.nms.mask[0][3];
    for (int i = 0; i < KK; ++i) {
      u64 c0 = n0, c1 = n1, c2 = n2, c3 = n3;
      if (i + 1 < KK) {  // prefetch next row (broadcast LDS read)
        n0 = sm.u.nms.mask[i + 1][0];
        n1 = sm.u.nms.mask[i + 1][1];
        n2 = sm.u.nms.mask[i + 1][2];
        n3 = sm.u.nms.mask[i + 1][3];
      }
      const int w = i >> 6;
      const u64 bitm = 1ull << (i & 63);
      u64 sw = (w == 0) ? s0_ : (w == 1) ? s1_ : (w == 2) ? s2_ : s3_;
      if (!(sw & bitm)) {
        if (w == 0) k0_ |= bitm;
        else if (w == 1) k1_ |= bitm;
        else if (w == 2) k2_ |= bitm;
        else k3_ |= bitm;
        s0_ |= c0; s1_ |= c1; s2_ |= c2; s3_ |= c3;
      }
    }
  }

  // ---- phase 8: compacted output (every row in [0,200) written exactly once) ----
  if (t < KK) {
    const int w = t >> 6;
    const int bit = t & 63;
    u64 kw = (w == 0) ? k0_ : (w == 1) ? k1_ : (w == 2) ? k2_ : k3_;
    bool kp = (kw >> bit) & 1ull;
    int nk = __popcll(k0_) + __popcll(k1_) + __popcll(k2_) + __popcll(k3_);
    if (kp) {
      u64 lowm = (bit == 0) ? 0ull : (~0ull >> (64 - bit));
      int d = __popcll(kw & lowm);
      if (w > 0) d += __popcll(k0_);
      if (w > 1) d += __popcll(k1_);
      if (w > 2) d += __popcll(k2_);
      float* o = out + outbase + (size_t)d * 5;
      o[0] = sm.u.nms.bscore[t];
      o[1] = sm.u.nms.bx1[t];
      o[2] = sm.u.nms.by1[t];
      o[3] = sm.u.nms.bx2[t];
      o[4] = sm.u.nms.by2[t];
    }
    if (t >= nk) {
      float* o = out + outbase + (size_t)t * 5;
      o[0] = 0.f; o[1] = 0.f; o[2] = 0.f; o[3] = 0.f; o[4] = 0.f;
    }
  }
}

// ---------------- launch ----------------
extern "C" void kernel_launch(void* const* d_in, const int* in_sizes, int n_in,
                              void* d_out, int out_size, void* d_ws, size_t ws_size,
                              hipStream_t stream) {
  (void)in_sizes; (void)n_in; (void)out_size;
  const float* loc = (const float*)d_in[0];
  const float* conf = (const float*)d_in[1];
  const float* dbox = (const float*)d_in[2];
  float* out = (float*)d_out;

  const size_t needA = (size_t)BB * 20 * NN * sizeof(float);    // 178.8 MB transposed probs
  const size_t needB = (size_t)BB * NN * sizeof(double2);       // 35.8 MB {max, 1/S}
  dim3 blk(TPB);
  dim3 g1((NN + TPB - 1) / TPB, BB);
  const int g2 = BB * CC;

  if (ws_size >= needA) {
    float* probsT = (float*)d_ws;
    prep_kernel<0><<<g1, blk, 0, stream>>>(conf, probsT, nullptr);
    nms_kernel<0><<<g2, blk, 0, stream>>>(probsT, conf, nullptr, loc, dbox, out);
  } else if (ws_size >= needB) {
    double2* msp = (double2*)d_ws;
    prep_kernel<1><<<g1, blk, 0, stream>>>(conf, nullptr, msp);
    nms_kernel<1><<<g2, blk, 0, stream>>>(nullptr, conf, msp, loc, dbox, out);
  } else {
    nms_kernel<2><<<g2, blk, 0, stream>>>(nullptr, conf, nullptr, loc, dbox, out);
  }
}

// Round 2
// 669.420 us; speedup vs baseline: 1.2642x; 1.2642x over previous
//
#include <hip/hip_runtime.h>
#include <cstdint>

#pragma clang fp contract(off)

#define TPB 256
typedef unsigned int uint32;
typedef unsigned long long u64;

constexpr int BB = 256;    // batch
constexpr int NN = 8732;   // boxes
constexpr int CC = 21;     // classes
constexpr int KK = 200;    // top-k
constexpr int CH = (NN + TPB - 1) / TPB;  // 35 elems per thread chunk (contiguous, index-ordered)
constexpr uint32 SENT = 0x407FFFFFu;      // key for masked (-1.0f) entries

// ---------------- shared memory layout ----------------
struct NmsS {
  alignas(16) float bx1[256];
  alignas(16) float by1[256];
  alignas(16) float bx2[256];
  alignas(16) float by2[256];
  alignas(16) float barea[256];
  alignas(16) float bscore[256];
  alignas(16) u64 mask[KK][4];   // 6400 B
  u64 kept[4];
};
struct SmemT {
  union alignas(16) UU {
    uint32 keys[NN];   // 34928 B  (select phase)
    NmsS nms;          // ~12.6 KB (NMS phase; keys dead by then)
  } u;
  uint32 hist[256];
  uint32 sc4[4];
  uint32 bc[2];
  uint32 vcnt;
  uint32 slot;
  alignas(16) u64 cand[256];
};
static_assert(sizeof(SmemT) <= 40 * 1024, "LDS budget for 4 blocks/CU");

// monotone sortable key; masked(-1.0f) maps to SENT; probs > 0.01 get top bit set
__device__ __forceinline__ uint32 key_of(float p) {
  return (p > 0.01f) ? (__float_as_uint(p) | 0x80000000u) : SENT;
}

// ---------------- kernel 1: canonical double-precision softmax ----------------
// LDS-staged coalesced loads; math identical (op order preserved) to validated r1.
template <int MODE>
__global__ __launch_bounds__(TPB) void prep_kernel(const float* __restrict__ conf,
                                                   float* __restrict__ probsT,
                                                   double2* __restrict__ ms) {
  __shared__ float tile[TPB * CC];  // 21504 B
  const int blk = blockIdx.x;
  const int b = blockIdx.y;
  const int n0 = blk * TPB;
  const int cnt = (NN - n0 < TPB) ? (NN - n0) : TPB;
  const size_t base = ((size_t)b * NN + n0) * CC;
  if (cnt == TPB) {
    const float4* s4 = (const float4*)(conf + base);  // base*4B is 16-aligned
    float4* t4 = (float4*)tile;
    for (int i = threadIdx.x; i < (TPB * CC) / 4; i += TPB) t4[i] = s4[i];
  } else {
    for (int i = threadIdx.x; i < cnt * CC; i += TPB) tile[i] = conf[base + i];
  }
  __syncthreads();
  if (threadIdx.x >= cnt) return;
  const int n = n0 + threadIdx.x;
  const float* cp = tile + threadIdx.x * CC;  // stride-21: 2-way bank alias = free
  float xs[CC];
#pragma unroll
  for (int j = 0; j < CC; ++j) xs[j] = cp[j];
  float mx = xs[0];
#pragma unroll
  for (int j = 1; j < CC; ++j) mx = fmaxf(mx, xs[j]);
  double es[CC];
  double S = 0.0;
#pragma unroll
  for (int j = 0; j < CC; ++j) {
    es[j] = exp((double)xs[j] - (double)mx);
    S += es[j];
  }
  double Sinv = 1.0 / S;
  if (MODE == 0) {
#pragma unroll
    for (int c2 = 1; c2 < CC; ++c2)
      probsT[((size_t)b * 20 + (c2 - 1)) * NN + n] = (float)(es[c2] * Sinv);
  } else {
    ms[(size_t)b * NN + n] = make_double2((double)mx, Sinv);
  }
}

// ---------------- kernel 2: per-(b,c) top-k + NMS + output ----------------
template <int MODE>
__global__ __launch_bounds__(TPB, 4) void nms_kernel(
    const float* __restrict__ probsT, const float* __restrict__ conf,
    const double2* __restrict__ ms, const float* __restrict__ loc,
    const float* __restrict__ dbox, float* __restrict__ out) {
  __shared__ SmemT sm;
  const int t = threadIdx.x;
  const int lane = t & 63;
  const int wv = t >> 6;
  // XCD-locality swizzle
  const int tb = blockIdx.x;
  const int xcd = tb & 7;
  const int s0i = tb >> 3;
  const int bi = s0i / CC;
  const int c = s0i - bi * CC;
  const int b = bi * 8 + xcd;
  const size_t outbase = (size_t)(b * CC + c) * KK * 5;

  if (c == 0) {  // reference zeroes class 0
    for (int i = t; i < KK * 5; i += TPB) out[outbase + i] = 0.0f;
    return;
  }

  if (t == 0) { sm.vcnt = 0u; sm.slot = 0u; }
  if (t < 256) sm.hist[t] = 0u;

  // ---- phase 1: build sortable keys in LDS + count valid ----
  uint32 vc = 0;
  if (MODE == 0) {
    const float4* pp4 = (const float4*)(probsT + ((size_t)b * 20 + (c - 1)) * NN);
    uint4* kv4 = (uint4*)sm.u.keys;
    for (int i = t; i < NN / 4; i += TPB) {
      float4 p = pp4[i];
      vc += (p.x > 0.01f) + (p.y > 0.01f) + (p.z > 0.01f) + (p.w > 0.01f);
      kv4[i] = make_uint4(key_of(p.x), key_of(p.y), key_of(p.z), key_of(p.w));
    }
  } else if (MODE == 1) {
    for (int n = t; n < NN; n += TPB) {
      double2 mv = ms[(size_t)b * NN + n];
      float x = conf[((size_t)b * NN + n) * CC + c];
      float p = (float)(exp((double)x - mv.x) * mv.y);
      vc += (p > 0.01f);
      sm.u.keys[n] = key_of(p);
    }
  } else {
    for (int n = t; n < NN; n += TPB) {
      const float* cp = conf + ((size_t)b * NN + n) * CC;
      float mx = cp[0];
      for (int j = 1; j < CC; ++j) mx = fmaxf(mx, cp[j]);
      double S = 0.0, ec = 0.0;
      for (int j = 0; j < CC; ++j) {
        double e = exp((double)cp[j] - (double)mx);
        S += e;
        if (j == c) ec = e;
      }
      float p = (float)(ec * (1.0 / S));
      vc += (p > 0.01f);
      sm.u.keys[n] = key_of(p);
    }
  }
  __syncthreads();
  for (int off = 32; off; off >>= 1) vc += __shfl_xor(vc, off, 64);
  if (lane == 0) atomicAdd(&sm.vcnt, vc);
  __syncthreads();
  const uint32 validCount = sm.vcnt;

  // ---- phase 2: exact select of 200th key: 4x8-bit radix (sentinels excluded) ----
  uint32 T, cnt_gt;
  if (validCount >= (uint32)KK) {
    uint32 pref = 0, target = (uint32)KK;
    cnt_gt = 0;
    for (int pass = 0; pass < 4; ++pass) {
      const int sh = 24 - 8 * pass;
      const int sh8 = (sh + 8) & 31;  // masked to dodge UB if speculated
      const uint4* kv4 = (const uint4*)sm.u.keys;
      for (int i = t; i < NN / 4; i += TPB) {
        uint4 kv = kv4[i];
#pragma unroll
        for (int e = 0; e < 4; ++e) {
          uint32 k = (e == 0) ? kv.x : (e == 1) ? kv.y : (e == 2) ? kv.z : kv.w;
          bool m = (pass == 0) ? ((k & 0x80000000u) != 0u) : ((k >> sh8) == pref);
          if (m) atomicAdd(&sm.hist[(k >> sh) & 255u], 1u);
        }
      }
      __syncthreads();
      uint32 h = sm.hist[t];
      uint32 suf = h;
      for (int off = 1; off < 64; off <<= 1) {
        uint32 u = __shfl_down(suf, off, 64);
        if (lane + off < 64) suf += u;
      }
      if (lane == 0) sm.sc4[wv] = suf;
      __syncthreads();
      sm.hist[t] = 0u;  // clear for next pass (h already read)
      uint32 add = 0;
      for (int w = wv + 1; w < 4; ++w) add += sm.sc4[w];
      uint32 mine = suf + add, nxt = mine - h;
      if (mine >= target && nxt < target) { sm.bc[0] = (uint32)t; sm.bc[1] = nxt; }
      __syncthreads();
      uint32 pivot = sm.bc[0], cg = sm.bc[1];
      pref = (pref << 8) | pivot;
      cnt_gt += cg;
      target -= cg;
    }
    T = pref;
  } else {
    T = SENT;
    cnt_gt = validCount;
  }
  const uint32 m_need = (uint32)KK - cnt_gt;  // equal-to-T to take, lowest index first

  // ---- phase 3: stable selection of exactly 200 candidates ----
  sm.cand[t] = 0ull;  // padding sorts last
  __syncthreads();
  const int base = t * CH;
  const int endn = (base + CH < NN) ? (base + CH) : NN;
  for (int n = base; n < endn; ++n) {
    uint32 k = sm.u.keys[n];
    if (k > T) {
      uint32 slot = atomicAdd(&sm.slot, 1u);
      sm.cand[slot] = ((u64)k << 32) | (uint32)(~(uint32)n);
    }
  }
  uint32 cnteq = 0;
  for (int n = base; n < endn; ++n)
    if (sm.u.keys[n] == T) ++cnteq;
  uint32 incl = cnteq;
  for (int off = 1; off < 64; off <<= 1) {
    uint32 u = __shfl_up(incl, off, 64);
    if (lane >= off) incl += u;
  }
  if (lane == 63) sm.sc4[wv] = incl;
  __syncthreads();
  uint32 add = 0;
  for (int w = 0; w < wv; ++w) add += sm.sc4[w];
  uint32 g = add + incl - cnteq;  // exclusive rank among equals, global index order
  for (int n = base; n < endn; ++n) {
    if (sm.u.keys[n] == T) {
      if (g < m_need) sm.cand[cnt_gt + g] = ((u64)T << 32) | (uint32)(~(uint32)n);
      ++g;
    }
  }
  __syncthreads();

  // ---- phase 4: bitonic sort 256 in registers (key desc, idx asc) ----
  u64 val = sm.cand[t];
  for (int kk = 2; kk <= 256; kk <<= 1) {
    for (int j = kk >> 1; j > 0; j >>= 1) {
      u64 other;
      if (j >= 64) {
        __syncthreads();
        sm.cand[t] = val;
        __syncthreads();
        other = sm.cand[t ^ j];
      } else {
        other = __shfl_xor((unsigned long long)val, j, 64);
      }
      const bool takeMax = ((t & kk) == 0) == ((t & j) == 0);
      val = takeMax ? (val > other ? val : other) : (val < other ? val : other);
    }
  }

  // ---- phase 5: gather + decode (exact reference fp32 op order, CR exp) ----
  if (t < KK) {
    uint32 k32 = (uint32)(val >> 32);
    uint32 idx = ~((uint32)val);
    bool valid = (k32 & 0x80000000u) != 0u;
    float score = valid ? __uint_as_float(k32 & 0x7fffffffu) : -1.0f;
    const float4 lc = ((const float4*)loc)[(size_t)b * NN + idx];
    const float4 db = ((const float4*)dbox)[idx];
    float cx = db.x + (lc.x * 0.1f) * db.z;
    float cy = db.y + (lc.y * 0.1f) * db.w;
    float w_ = db.z * (float)exp((double)(lc.z * 0.2f));
    float h_ = db.w * (float)exp((double)(lc.w * 0.2f));
    float x1 = cx - w_ * 0.5f;
    float y1 = cy - h_ * 0.5f;
    float x2 = x1 + w_;
    float y2 = y1 + h_;
    sm.u.nms.bx1[t] = x1;
    sm.u.nms.by1[t] = y1;
    sm.u.nms.bx2[t] = x2;
    sm.u.nms.by2[t] = y2;
    sm.u.nms.barea[t] = (x2 - x1) * (y2 - y1);
    sm.u.nms.bscore[t] = score;
  } else {
    sm.u.nms.bscore[t] = -1.0f;  // defined for the phase-7 ballots
  }
  __syncthreads();

  // ---- phase 6: directional IoU mask rows (b128 box loads, rcp fast path) ----
  if (t < KK) {
    const float xi1 = sm.u.nms.bx1[t], yi1 = sm.u.nms.by1[t];
    const float xi2 = sm.u.nms.bx2[t], yi2 = sm.u.nms.by2[t];
    const float ai = sm.u.nms.barea[t];
#pragma unroll
    for (int wq = 0; wq < 4; ++wq) {
      const int jbeg = wq * 64;
      const int jend = (jbeg + 64 < KK) ? (jbeg + 64) : KK;
      u64 w = 0;
      for (int j0 = jbeg; j0 < jend; j0 += 4) {
        const float4 q1 = *(const float4*)&sm.u.nms.bx1[j0];
        const float4 q2 = *(const float4*)&sm.u.nms.by1[j0];
        const float4 q3 = *(const float4*)&sm.u.nms.bx2[j0];
        const float4 q4 = *(const float4*)&sm.u.nms.by2[j0];
        const float4 qa = *(const float4*)&sm.u.nms.barea[j0];
        const float a1[4] = {q1.x, q1.y, q1.z, q1.w};
        const float a2[4] = {q2.x, q2.y, q2.z, q2.w};
        const float a3[4] = {q3.x, q3.y, q3.z, q3.w};
        const float a4[4] = {q4.x, q4.y, q4.z, q4.w};
        const float aa[4] = {qa.x, qa.y, qa.z, qa.w};
#pragma unroll
        for (int e = 0; e < 4; ++e) {
          const int j = j0 + e;
          float xx1 = fmaxf(a1[e], xi1);
          float yy1 = fmaxf(a2[e], yi1);
          float xx2 = fmaxf(a3[e], xi2);
          float yy2 = fmaxf(a4[e], yi2);
          float inter = (xx2 - xx1) * (yy2 - yy1);   // NOT clamped (ref!)
          float uni = (aa[e] - inter) + ai;          // exact ref op order
          float r = __builtin_amdgcn_rcpf(uni);
          float q = inter * r;                       // |err| < ~1.2e-7 rel
          bool sup = q > 0.45f;
          if (__builtin_expect(fabsf(q - 0.45f) <= 2e-5f, 0))
            sup = (inter / uni) > 0.45f;             // exact IEEE fallback in band
          if (sup && j != t) w |= 1ull << (j & 63);
        }
      }
      sm.u.nms.mask[t][wq] = w;
    }
  }
  __syncthreads();

  // ---- phase 7: greedy walk on wave 0 only (results to LDS) ----
  if (wv == 0) {
    u64 s0 = __ballot(!(sm.u.nms.bscore[lane] > 0.01f));
    u64 s1 = __ballot(!(sm.u.nms.bscore[64 + lane] > 0.01f));
    u64 s2 = __ballot(!(sm.u.nms.bscore[128 + lane] > 0.01f));
    u64 s3 = __ballot(!(sm.u.nms.bscore[192 + lane] > 0.01f)) | ~0xFFull;
    u64 k0 = 0, k1 = 0, k2 = 0, k3 = 0;
    const u64(*M)[4] = sm.u.nms.mask;
    u64 n0 = M[0][0], n1 = M[0][1], n2 = M[0][2], n3 = M[0][3];
    int i = 0;
#define WALK_BLOCK(SW, KW, CNT)                                          \
  for (int ii = 0; ii < (CNT); ++ii, ++i) {                              \
    u64 c0 = n0, c1 = n1, c2 = n2, c3 = n3;                              \
    if (i + 1 < KK) {                                                    \
      n0 = M[i + 1][0]; n1 = M[i + 1][1];                                \
      n2 = M[i + 1][2]; n3 = M[i + 1][3];                                \
    }                                                                    \
    u64 bm = 1ull << ii;                                                 \
    if (!((SW) & bm)) {                                                  \
      (KW) |= bm;                                                        \
      s0 |= c0; s1 |= c1; s2 |= c2; s3 |= c3;                            \
    }                                                                    \
  }
    WALK_BLOCK(s0, k0, 64)
    WALK_BLOCK(s1, k1, 64)
    WALK_BLOCK(s2, k2, 64)
    WALK_BLOCK(s3, k3, 8)
#undef WALK_BLOCK
    if (lane == 0) {
      sm.u.nms.kept[0] = k0; sm.u.nms.kept[1] = k1;
      sm.u.nms.kept[2] = k2; sm.u.nms.kept[3] = k3;
    }
  }
  __syncthreads();

  // ---- phase 8: compacted output ----
  if (t < KK) {
    const u64 K0 = sm.u.nms.kept[0], K1 = sm.u.nms.kept[1];
    const u64 K2 = sm.u.nms.kept[2], K3 = sm.u.nms.kept[3];
    const int w = t >> 6;
    const int bit = t & 63;
    u64 kw = (w == 0) ? K0 : (w == 1) ? K1 : (w == 2) ? K2 : K3;
    bool kp = (kw >> bit) & 1ull;
    int nk = __popcll(K0) + __popcll(K1) + __popcll(K2) + __popcll(K3);
    if (kp) {
      u64 lowm = (bit == 0) ? 0ull : (~0ull >> (64 - bit));
      int d = __popcll(kw & lowm);
      if (w > 0) d += __popcll(K0);
      if (w > 1) d += __popcll(K1);
      if (w > 2) d += __popcll(K2);
      float* o = out + outbase + (size_t)d * 5;
      o[0] = sm.u.nms.bscore[t];
      o[1] = sm.u.nms.bx1[t];
      o[2] = sm.u.nms.by1[t];
      o[3] = sm.u.nms.bx2[t];
      o[4] = sm.u.nms.by2[t];
    }
    if (t >= nk) {
      float* o = out + outbase + (size_t)t * 5;
      o[0] = 0.f; o[1] = 0.f; o[2] = 0.f; o[3] = 0.f; o[4] = 0.f;
    }
  }
}

// ---------------- launch ----------------
extern "C" void kernel_launch(void* const* d_in, const int* in_sizes, int n_in,
                              void* d_out, int out_size, void* d_ws, size_t ws_size,
                              hipStream_t stream) {
  (void)in_sizes; (void)n_in; (void)out_size;
  const float* loc = (const float*)d_in[0];
  const float* conf = (const float*)d_in[1];
  const float* dbox = (const float*)d_in[2];
  float* out = (float*)d_out;

  const size_t needA = (size_t)BB * 20 * NN * sizeof(float);  // 178.8 MB transposed probs
  const size_t needB = (size_t)BB * NN * sizeof(double2);     // 35.8 MB {max, 1/S}
  dim3 blk(TPB);
  dim3 g1((NN + TPB - 1) / TPB, BB);
  const int g2 = BB * CC;

  if (ws_size >= needA) {
    float* probsT = (float*)d_ws;
    prep_kernel<0><<<g1, blk, 0, stream>>>(conf, probsT, nullptr);
    nms_kernel<0><<<g2, blk, 0, stream>>>(probsT, conf, nullptr, loc, dbox, out);
  } else if (ws_size >= needB) {
    double2* msp = (double2*)d_ws;
    prep_kernel<1><<<g1, blk, 0, stream>>>(conf, nullptr, msp);
    nms_kernel<1><<<g2, blk, 0, stream>>>(nullptr, conf, msp, loc, dbox, out);
  } else {
    nms_kernel<2><<<g2, blk, 0, stream>>>(nullptr, conf, nullptr, loc, dbox, out);
  }
}